// Round 1
// baseline (10186.105 us; speedup 1.0000x reference)
//
#include <hip/hip_runtime.h>
#include <stdint.h>

// Stage2 neural-dynamics simulator, MI355X.
// Design A: one block per batch element (64 blocks), zero inter-block sync.
// Combined sparse matrix M = [DT*sign*softplus(Wsv)*mask | DT*sign*softplus(Wdcv)*mask | DT*G*Te]
// acting on z = [y_sv | y_dcv | u] (900 floats in LDS). Entries packed as
// (bf16 value << 16) | column, stored ELL-transposed with rows rank-sorted by
// nnz so each wave's loop bound ~= its rows' mean length.

#define NN      300
#define TPB     320
#define NWAVE   5
#define TSTEPS  1000
#define DDIM    32
#define BATCH   64
#define KMAX    256
#define DTC     0.01f
#define UCLIP   35.0f

// ws layout (bytes)
#define ENT_OFF   0
#define ENT_BYTES (KMAX*TPB*4)           // 327680
#define CR_OFF    (ENT_OFF+ENT_BYTES)    // f32[TPB]  c[i] = lam - DT*G*deg, rank-ordered
#define DR_OFF    (CR_OFF+TPB*4)         // f32[TPB]  DT*I0[i], rank-ordered
#define RR_OFF    (DR_OFF+TPB*4)         // u32[TPB]  rank -> row
#define LW_OFF    (RR_OFF+TPB*4)         // u32[8]    per-wave loop bound
#define META_OFF  (LW_OFF+8*4)           // f32[16]   alpha x4, gamma x4

__device__ __forceinline__ float sigmoidf_(float x){ return 1.0f/(1.0f+__expf(-x)); }
__device__ __forceinline__ float softplusf_(float x){ return x>15.f ? x : log1pf(__expf(x)); }

__device__ __forceinline__ uint32_t bf16bits(float f){
  uint32_t v = __float_as_uint(f);
  return (v + 0x7FFFu + ((v>>16)&1u)) >> 16;   // RN-even
}

__global__ __launch_bounds__(TPB) void prep_kernel(
    const float* __restrict__ Te,  const float* __restrict__ Tsv,
    const float* __restrict__ Tdcv,const float* __restrict__ Wsv,
    const float* __restrict__ Wdcv,const float* __restrict__ lamr,
    const float* __restrict__ Gr,  const float* __restrict__ I0,
    const float* __restrict__ asvr,const float* __restrict__ tausvr,
    const float* __restrict__ adcvr,const float* __restrict__ taudcvr,
    const int*   __restrict__ signt, uint8_t* __restrict__ ws)
{
  __shared__ uint32_t len_s[TPB];
  __shared__ uint32_t rr_s[TPB];
  __shared__ float    sgn_s[NN];
  __shared__ uint32_t lw_s[NWAVE];
  int tid = threadIdx.x;
  uint32_t* ENT = (uint32_t*)(ws + ENT_OFF);
  float*    CR  = (float*)(ws + CR_OFF);
  float*    DR  = (float*)(ws + DR_OFF);
  uint32_t* RR  = (uint32_t*)(ws + RR_OFF);
  uint32_t* LWg = (uint32_t*)(ws + LW_OFF);
  float*    META= (float*)(ws + META_OFF);

  float G = 2.0f * sigmoidf_(Gr[0]);

  if (tid < NN) sgn_s[tid] = 2.0f*(float)signt[tid] - 1.0f;
  rr_s[tid] = 0xFFFFFFFFu;

  // pass A: row lengths + gap-junction degree
  float deg = 0.f; uint32_t cnt = 0;
  if (tid < NN) {
    const float* te  = Te   + tid*NN;
    const float* tsv = Tsv  + tid*NN;
    const float* tdv = Tdcv + tid*NN;
    for (int j=0;j<NN;++j){
      float e = te[j];
      deg += e;
      cnt += (tsv[j] > 0.f) ? 1u:0u;
      cnt += (tdv[j] > 0.f) ? 1u:0u;
      cnt += (e      > 0.f) ? 1u:0u;
    }
  }
  len_s[tid] = (tid<NN)?cnt:0u;
  __syncthreads();

  // pass B: rank rows by descending nnz (ties by index) for wave load balance
  uint32_t rank=0;
  if (tid < NN){
    uint32_t li = cnt;
    for (int j=0;j<NN;++j){
      uint32_t lj = len_s[j];
      rank += (lj>li || (lj==li && j<tid)) ? 1u:0u;
    }
    rr_s[rank] = (uint32_t)tid;
  }
  __syncthreads();
  if (tid < NWAVE){
    uint32_t L = len_s[rr_s[tid*64]];   // longest row in this wave (sorted desc)
    L = (L+3u)&~3u;
    if (L > KMAX) L = KMAX;
    lw_s[tid] = L; LWg[tid] = L;
  }
  if (tid >= NWAVE && tid < 8) LWg[tid] = 0;
  RR[tid] = rr_s[tid];
  __syncthreads();

  // pass C: emit packed entries at this row's rank column
  if (tid < NN){
    int i = tid;
    uint32_t r  = rank;
    uint32_t lw = lw_s[r>>6];
    const float* te  = Te   + i*NN;
    const float* tsv = Tsv  + i*NN;
    const float* tdv = Tdcv + i*NN;
    const float* wsv = Wsv  + i*NN;
    const float* wdv = Wdcv + i*NN;
    uint32_t k=0;
    for (int j=0;j<NN;++j){
      if (tsv[j] > 0.f && k<lw){
        float v = DTC * sgn_s[j] * softplusf_(wsv[j]);
        ENT[k*TPB + r] = (bf16bits(v)<<16) | (uint32_t)j;  ++k;
      }
    }
    for (int j=0;j<NN;++j){
      if (tdv[j] > 0.f && k<lw){
        float v = DTC * sgn_s[j] * softplusf_(wdv[j]);
        ENT[k*TPB + r] = (bf16bits(v)<<16) | (uint32_t)(NN+j);  ++k;
      }
    }
    for (int j=0;j<NN;++j){
      if (te[j] > 0.f && k<lw){
        float v = DTC * G * te[j];
        ENT[k*TPB + r] = (bf16bits(v)<<16) | (uint32_t)(2*NN+j);  ++k;
      }
    }
    for (; k<lw; ++k) ENT[k*TPB + r] = (uint32_t)(3*NN);  // val=0, idx=900 (zs[900]=0)
    float lam = 0.9999f * sigmoidf_(lamr[i]);
    CR[r] = lam - DTC*G*deg;
    DR[r] = DTC * I0[i];
  } else {
    CR[tid] = 0.f; DR[tid] = 0.f;   // inert rank slots 300..319
  }
  if (tid < 4){
    const float* ar = (tid<2)? asvr   : adcvr;
    const float* tr = (tid<2)? tausvr : taudcvr;
    int kk = tid & 1;
    float a   = 10.0f * sigmoidf_(ar[kk]);
    float tau = softplusf_(tr[kk]) + 1e-4f;
    float al  = __expf(-DTC/tau);
    META[tid]   = al;            // alpha
    META[4+tid] = a*(1.0f-al);   // gamma = a*(1-alpha); track s' = a*s
  }
}

__global__ __launch_bounds__(TPB) void sim_kernel(
    const float* __restrict__ x, const float* __restrict__ u0,
    const float* __restrict__ bmat, const uint8_t* __restrict__ ws,
    float* __restrict__ out)
{
  __shared__ float zs[3*NN+4];
  const uint32_t* ENT = (const uint32_t*)(ws + ENT_OFF);
  const float*    CR  = (const float*)(ws + CR_OFF);
  const float*    DR  = (const float*)(ws + DR_OFF);
  const uint32_t* RR  = (const uint32_t*)(ws + RR_OFF);
  const uint32_t* LWg = (const uint32_t*)(ws + LW_OFF);
  const float*    META= (const float*)(ws + META_OFF);

  int tid = threadIdx.x;
  int b   = blockIdx.x;
  uint32_t row = RR[tid];
  bool act = row < NN;

  float al0=META[0], al1=META[1], al2=META[2], al3=META[3];
  float g0 =META[4], g1 =META[5], g2 =META[6], g3 =META[7];

  float c=0.f, dterm=0.f, u=0.f;
  float s0=0.f,s1=0.f,s2=0.f,s3=0.f;
  float breg[DDIM];
  #pragma unroll
  for (int d=0;d<DDIM;++d) breg[d]=0.f;
  if (act){
    c = CR[tid]; dterm = DR[tid];
    u = u0[b*NN + row];
    #pragma unroll
    for (int d=0;d<DDIM;++d) breg[d] = bmat[row*DDIM + d];
  }
  int Lw = (int)LWg[tid>>6];      // wave-uniform loop bound
  if (tid == 0) zs[3*NN] = 0.f;   // pad-entry target

  const float* xb = x   + (size_t)b*TSTEPS*DDIM;
  float*       ob = out + (size_t)b*TSTEPS*NN;

  for (int t=0; t<TSTEPS; ++t){
    if (act){
      float phi = 1.0f/(1.0f+__expf(-u));
      s0 = fmaf(al0, s0, g0*phi);
      s1 = fmaf(al1, s1, g1*phi);
      s2 = fmaf(al2, s2, g2*phi);
      s3 = fmaf(al3, s3, g3*phi);
      zs[row]      = s0+s1;   // y_sv  (s' = a*s tracked)
      zs[NN+row]   = s2+s3;   // y_dcv
      zs[2*NN+row] = u;
    }
    __syncthreads();

    float acc = 0.f;
    if (act){
      #pragma unroll 4
      for (int k=0;k<Lw;++k){
        uint32_t e = ENT[k*TPB + tid];
        float val = __uint_as_float(e & 0xFFFF0000u);
        float zv  = zs[e & 0xFFFFu];
        acc = fmaf(val, zv, acc);
      }
    }

    float stim = 0.f;
    {
      const float4* xt = (const float4*)(xb + t*DDIM);
      #pragma unroll
      for (int q=0;q<DDIM/4;++q){
        float4 xv = xt[q];
        stim = fmaf(breg[4*q+0], xv.x, stim);
        stim = fmaf(breg[4*q+1], xv.y, stim);
        stim = fmaf(breg[4*q+2], xv.z, stim);
        stim = fmaf(breg[4*q+3], xv.w, stim);
      }
    }
    __syncthreads();   // all gathers done before next step's z writes

    if (act){
      float un = fmaf(c, u, acc + dterm + DTC*stim);
      un = fminf(fmaxf(un, -UCLIP), UCLIP);
      u = un;
      ob[t*NN + row] = u;
    }
  }
}

extern "C" void kernel_launch(void* const* d_in, const int* in_sizes, int n_in,
                              void* d_out, int out_size, void* d_ws, size_t ws_size,
                              hipStream_t stream)
{
  const float* x      = (const float*)d_in[0];
  const float* u0v    = (const float*)d_in[1];
  const float* Te     = (const float*)d_in[2];
  const float* Tsv    = (const float*)d_in[3];
  const float* Tdcv   = (const float*)d_in[4];
  const float* Wsv    = (const float*)d_in[5];
  const float* Wdcv   = (const float*)d_in[6];
  const float* lamr   = (const float*)d_in[7];
  const float* Gr     = (const float*)d_in[8];
  const float* I0     = (const float*)d_in[9];
  const float* bmat   = (const float*)d_in[10];
  const float* asvr   = (const float*)d_in[11];
  const float* tausvr = (const float*)d_in[12];
  const float* adcvr  = (const float*)d_in[13];
  const float* taudcvr= (const float*)d_in[14];
  const int*   signt  = (const int*)d_in[15];
  uint8_t* ws = (uint8_t*)d_ws;

  hipLaunchKernelGGL(prep_kernel, dim3(1), dim3(TPB), 0, stream,
      Te, Tsv, Tdcv, Wsv, Wdcv, lamr, Gr, I0,
      asvr, tausvr, adcvr, taudcvr, signt, ws);
  hipLaunchKernelGGL(sim_kernel, dim3(BATCH), dim3(TPB), 0, stream,
      x, u0v, bmat, ws, (float*)d_out);
}

// Round 2
// 3591.502 us; speedup vs baseline: 2.8362x; 2.8362x over previous
//
#include <hip/hip_runtime.h>
#include <stdint.h>

// Stage2 neural-dynamics simulator, MI355X — round 2.
// 64 blocks (one per batch), 960 threads = 15 waves: rows rank-sorted by nnz,
// each row's entries split round-robin over 3 thread-parts (tid/320) to cut the
// serial gather chain 3x and triple latency-hiding waves. Entry stream stored
// uint4-grouped (4 slots per thread contiguous) for coalesced dwordx4 loads,
// consumed through an explicit 32-entry A/B register pipeline. Stimulus GEMM
// DT*(x@b^T) precomputed into d_out (sim reads cell then overwrites with u).

#define NN      300
#define PTPB    320      // rank slots / part width
#define STPB    960      // sim threads (3 parts x 320)
#define NWAVE   5        // waves per part
#define KB      96       // per-part slot capacity (mult of 32)
#define TSTEPS  1000
#define DDIM    32
#define BATCH   64
#define DTC     0.01f
#define UCLIP   35.0f
#define PADENT  3600u    // val=0 bf16, byte-offset 3600 -> zs[900]=0

// ws layout (bytes)
#define ENT_OFF   0
#define ENT_BYTES (3*KB*PTPB*4)            // 368640
#define CR_OFF    (ENT_OFF+ENT_BYTES)      // f32[320] c = lam - DT*G*deg (rank order)
#define DR_OFF    (CR_OFF+PTPB*4)          // f32[320] DT*I0 (rank order)
#define RR_OFF    (DR_OFF+PTPB*4)          // u32[320] rank -> row
#define LW_OFF    (RR_OFF+PTPB*4)          // u32[8]   per-state-wave per-part bound
#define META_OFF  (LW_OFF+8*4)             // f32[8]   alpha x4, gamma x4
#define LEN_OFF   (META_OFF+8*4)           // u32[320] row nnz
#define DEG_OFF   (LEN_OFF+PTPB*4)         // f32[300] gap degree
#define RANK_OFF  (DEG_OFF+NN*4)           // u32[300] row -> rank

__device__ __forceinline__ float sigmoidf_(float x){ return 1.0f/(1.0f+__expf(-x)); }
__device__ __forceinline__ float softplusf_(float x){ return x>15.f ? x : log1pf(__expf(x)); }
__device__ __forceinline__ uint32_t bf16bits(float f){
  uint32_t v = __float_as_uint(f);
  return (v + 0x7FFFu + ((v>>16)&1u)) >> 16;   // RN-even
}
// entry s (0..3*lw) of rank r -> word index in ENT (uint4-grouped layout)
__device__ __forceinline__ uint32_t ent_widx(uint32_t s, uint32_t r){
  uint32_t part = s % 3u, slot = s / 3u;
  uint32_t sg = part*KB + slot;
  return ((sg>>2)*PTPB + r)*4u + (sg&3u);
}

// ---------- prep A: per-row nnz + gap degree (grid 300 x 64) ----------
__global__ __launch_bounds__(64) void prepA_kernel(
    const float* __restrict__ Te, const float* __restrict__ Tsv,
    const float* __restrict__ Tdcv, uint8_t* __restrict__ ws)
{
  int i = blockIdx.x, lane = threadIdx.x;
  const float* te  = Te   + (size_t)i*NN;
  const float* tsv = Tsv  + (size_t)i*NN;
  const float* tdv = Tdcv + (size_t)i*NN;
  uint32_t cnt = 0; float deg = 0.f;
  for (int j=lane; j<NN; j+=64){
    float e = te[j];
    deg += e;
    cnt += (tsv[j]>0.f) + (tdv[j]>0.f) + (e>0.f);
  }
  for (int off=32; off; off>>=1){
    cnt += __shfl_down(cnt, off);
    deg += __shfl_down(deg, off);
  }
  if (lane==0){
    ((uint32_t*)(ws+LEN_OFF))[i] = cnt;
    ((float*)(ws+DEG_OFF))[i]    = deg;
  }
}

// ---------- prep B: ranking + scalars (1 block x 320) ----------
__global__ __launch_bounds__(PTPB) void prepB_kernel(
    const float* __restrict__ lamr, const float* __restrict__ Gr,
    const float* __restrict__ I0,   const float* __restrict__ asvr,
    const float* __restrict__ tausvr, const float* __restrict__ adcvr,
    const float* __restrict__ taudcvr, uint8_t* __restrict__ ws)
{
  __shared__ uint32_t len_s[PTPB];
  __shared__ uint32_t rr_s[PTPB];
  int tid = threadIdx.x;
  uint32_t* LEN  = (uint32_t*)(ws+LEN_OFF);
  float*    DEG  = (float*)(ws+DEG_OFF);
  uint32_t* RANK = (uint32_t*)(ws+RANK_OFF);
  uint32_t* RR   = (uint32_t*)(ws+RR_OFF);
  uint32_t* LWg  = (uint32_t*)(ws+LW_OFF);
  float*    CR   = (float*)(ws+CR_OFF);
  float*    DR   = (float*)(ws+DR_OFF);
  float*    META = (float*)(ws+META_OFF);

  len_s[tid] = (tid<NN) ? LEN[tid] : 0u;
  rr_s[tid]  = 0xFFFFFFFFu;
  __syncthreads();
  uint32_t rank = 0;
  if (tid < NN){
    uint32_t li = len_s[tid];
    for (int j=0;j<NN;++j){
      uint32_t lj = len_s[j];
      rank += (lj>li || (lj==li && j<tid)) ? 1u:0u;
    }
    rr_s[rank] = (uint32_t)tid;
    RANK[tid]  = rank;
  }
  __syncthreads();
  RR[tid] = rr_s[tid];
  if (tid < NWAVE){
    uint32_t L  = len_s[rr_s[tid*64]];        // longest row in wave (desc sort)
    uint32_t Lp = (L+2u)/3u;                  // per-part count bound
    Lp = (Lp+31u)&~31u;                       // mult of 32 for pipeline
    if (Lp > KB) Lp = KB;
    LWg[tid] = Lp;
  }
  if (tid>=NWAVE && tid<8) LWg[tid] = 0;
  float G = 2.0f * sigmoidf_(Gr[0]);
  if (tid < NN){
    float lam = 0.9999f * sigmoidf_(lamr[tid]);
    CR[rank] = lam - DTC*G*DEG[tid];
    DR[rank] = DTC * I0[tid];
  } else {
    CR[tid] = 0.f; DR[tid] = 0.f;
  }
  if (tid < 4){
    const float* ar = (tid<2)? asvr   : adcvr;
    const float* tr = (tid<2)? tausvr : taudcvr;
    int kk = tid & 1;
    float a   = 10.0f * sigmoidf_(ar[kk]);
    float tau = softplusf_(tr[kk]) + 1e-4f;
    float al  = __expf(-DTC/tau);
    META[tid]   = al;
    META[4+tid] = a*(1.0f-al);   // track s' = a*s
  }
}

// ---------- prep C: emit packed entries (grid 320 x 64) ----------
__global__ __launch_bounds__(64) void prepC_kernel(
    const float* __restrict__ Te,  const float* __restrict__ Tsv,
    const float* __restrict__ Tdcv,const float* __restrict__ Wsv,
    const float* __restrict__ Wdcv,const float* __restrict__ Gr,
    const int*   __restrict__ signt, uint8_t* __restrict__ ws)
{
  int bb = blockIdx.x, lane = threadIdx.x;
  uint32_t* ENT  = (uint32_t*)(ws+ENT_OFF);
  const uint32_t* RANK = (const uint32_t*)(ws+RANK_OFF);
  const uint32_t* LWg  = (const uint32_t*)(ws+LW_OFF);

  if (bb >= NN){                       // unowned rank slots: all pad
    uint32_t r = (uint32_t)bb;
    uint32_t cap = 3u*LWg[r>>6];
    for (uint32_t s=lane; s<cap; s+=64) ENT[ent_widx(s,r)] = PADENT;
    return;
  }
  int row = bb;
  uint32_t r   = RANK[row];
  uint32_t cap = 3u*LWg[r>>6];
  float G = 2.0f * sigmoidf_(Gr[0]);
  const float* te  = Te   + (size_t)row*NN;
  const float* tsv = Tsv  + (size_t)row*NN;
  const float* tdv = Tdcv + (size_t)row*NN;
  const float* wsv = Wsv  + (size_t)row*NN;
  const float* wdv = Wdcv + (size_t)row*NN;
  uint64_t lmask = ((uint64_t)1 << lane) - 1;
  uint32_t k = 0;
  for (int c0=0; c0<NN; c0+=64){       // SV segment
    int j = c0 + lane;
    bool on = (j<NN) && (tsv[j] > 0.f);
    uint64_t bal = __ballot(on);
    if (on){
      uint32_t s = k + (uint32_t)__popcll(bal & lmask);
      if (s < cap){
        float sg = 2.0f*(float)signt[j] - 1.0f;
        float v  = DTC * sg * softplusf_(wsv[j]);
        ENT[ent_widx(s,r)] = (bf16bits(v)<<16) | (uint32_t)(j*4);
      }
    }
    k += (uint32_t)__popcll(bal);
  }
  for (int c0=0; c0<NN; c0+=64){       // DCV segment
    int j = c0 + lane;
    bool on = (j<NN) && (tdv[j] > 0.f);
    uint64_t bal = __ballot(on);
    if (on){
      uint32_t s = k + (uint32_t)__popcll(bal & lmask);
      if (s < cap){
        float sg = 2.0f*(float)signt[j] - 1.0f;
        float v  = DTC * sg * softplusf_(wdv[j]);
        ENT[ent_widx(s,r)] = (bf16bits(v)<<16) | (uint32_t)((NN+j)*4);
      }
    }
    k += (uint32_t)__popcll(bal);
  }
  for (int c0=0; c0<NN; c0+=64){       // TE (gap) segment
    int j = c0 + lane;
    bool on = (j<NN) && (te[j] > 0.f);
    uint64_t bal = __ballot(on);
    if (on){
      uint32_t s = k + (uint32_t)__popcll(bal & lmask);
      if (s < cap){
        float v = DTC * G * te[j];
        ENT[ent_widx(s,r)] = (bf16bits(v)<<16) | (uint32_t)((2*NN+j)*4);
      }
    }
    k += (uint32_t)__popcll(bal);
  }
  for (uint32_t s=k+lane; s<cap; s+=64) ENT[ent_widx(s,r)] = PADENT;
}

// ---------- stimulus GEMM: d_out[b,t,i] = DT * dot(x[b,t,:], bmat[i,:]) ----------
__global__ __launch_bounds__(256) void stim_kernel(
    const float* __restrict__ x, const float* __restrict__ bmat,
    float* __restrict__ out)
{
  int64_t gid = (int64_t)blockIdx.x*256 + threadIdx.x;
  if (gid >= (int64_t)BATCH*TSTEPS*NN) return;
  int i = (int)(gid % NN);
  int64_t bt = gid / NN;
  const float4* xv = (const float4*)(x + bt*DDIM);
  const float4* bv = (const float4*)(bmat + (size_t)i*DDIM);
  float s = 0.f;
  #pragma unroll
  for (int q=0;q<DDIM/4;++q){
    float4 a = xv[q], w = bv[q];
    s = fmaf(a.x,w.x,s); s = fmaf(a.y,w.y,s);
    s = fmaf(a.z,w.z,s); s = fmaf(a.w,w.w,s);
  }
  out[gid] = DTC * s;
}

// ---------- main simulator ----------
#define ZREAD(e) (*(const float*)((const char*)zs + ((e) & 0xFFFFu)))
#define PROC(v)  do{ \
    acc0 = fmaf(__uint_as_float((v).x & 0xFFFF0000u), ZREAD((v).x), acc0); \
    acc1 = fmaf(__uint_as_float((v).y & 0xFFFF0000u), ZREAD((v).y), acc1); \
    acc2 = fmaf(__uint_as_float((v).z & 0xFFFF0000u), ZREAD((v).z), acc2); \
    acc3 = fmaf(__uint_as_float((v).w & 0xFFFF0000u), ZREAD((v).w), acc3); \
  }while(0)

__global__ __launch_bounds__(STPB) void sim_kernel(
    const float* __restrict__ u0, const uint8_t* __restrict__ ws,
    float* __restrict__ out)
{
  __shared__ float zs[3*NN+4];     // [y_sv | y_dcv | u | pad], zs[900]=0
  __shared__ float pbuf[2*PTPB];   // partial sums from parts 1,2
  const float*    CR   = (const float*)(ws+CR_OFF);
  const float*    DR   = (const float*)(ws+DR_OFF);
  const uint32_t* RR   = (const uint32_t*)(ws+RR_OFF);
  const uint32_t* LWg  = (const uint32_t*)(ws+LW_OFF);
  const float*    META = (const float*)(ws+META_OFF);

  int tid = threadIdx.x;
  int b   = blockIdx.x;
  int p   = tid / PTPB;            // part 0..2
  int r   = tid - p*PTPB;          // rank slot 0..319
  int sw  = (tid>>6) % NWAVE;      // state-wave (parts are wave-aligned: 320=5*64)
  uint32_t row = RR[r];
  bool act = (p==0) && (row < NN);

  float al0=META[0], al1=META[1], al2=META[2], al3=META[3];
  float g0 =META[4], g1 =META[5], g2 =META[6], g3 =META[7];

  float c=0.f, dterm=0.f, u=0.f, s0=0.f,s1=0.f,s2=0.f,s3=0.f;
  if (act){ c = CR[r]; dterm = DR[r]; u = u0[(size_t)b*NN + row]; }
  int G4 = (int)(LWg[sw] >> 2);    // uint4 groups per part, multiple of 8
  const uint4* tp = ((const uint4*)(ws+ENT_OFF)) + (size_t)p*(KB/4)*PTPB + r;
  if (tid == STPB-1) zs[3*NN] = 0.f;
  float* ob = out + (size_t)b*TSTEPS*NN;

  for (int t=0; t<TSTEPS; ++t){
    if (act){
      float phi = 1.0f/(1.0f+__expf(-u));
      s0 = fmaf(al0, s0, g0*phi);
      s1 = fmaf(al1, s1, g1*phi);
      s2 = fmaf(al2, s2, g2*phi);
      s3 = fmaf(al3, s3, g3*phi);
      zs[row]      = s0+s1;
      zs[NN+row]   = s2+s3;
      zs[2*NN+row] = u;
    }
    __syncthreads();                       // B: z ready

    float stimv = 0.f;
    if (act) stimv = ob[t*NN + row];       // precomputed DT*stim (long-latency, hidden)

    float acc0=0.f, acc1=0.f, acc2=0.f, acc3=0.f;
    uint4 A0=tp[0], A1=tp[PTPB], A2=tp[2*PTPB], A3=tp[3*PTPB];
    for (int g=0; g<G4; g+=8){
      uint4 B0=tp[(size_t)(g+4)*PTPB], B1=tp[(size_t)(g+5)*PTPB],
            B2=tp[(size_t)(g+6)*PTPB], B3=tp[(size_t)(g+7)*PTPB];
      PROC(A0); PROC(A1); PROC(A2); PROC(A3);
      if (g+8 < G4){
        A0=tp[(size_t)(g+8)*PTPB];  A1=tp[(size_t)(g+9)*PTPB];
        A2=tp[(size_t)(g+10)*PTPB]; A3=tp[(size_t)(g+11)*PTPB];
      }
      PROC(B0); PROC(B1); PROC(B2); PROC(B3);
    }
    float acc = (acc0+acc1)+(acc2+acc3);
    if (p) pbuf[(p-1)*PTPB + r] = acc;
    __syncthreads();                       // C: partials ready

    if (act){
      float tot = acc + pbuf[r] + pbuf[PTPB+r];
      float un  = fmaf(c, u, tot + dterm + stimv);
      un = fminf(fmaxf(un, -UCLIP), UCLIP);
      u = un;
      ob[t*NN + row] = u;
    }
  }
}

extern "C" void kernel_launch(void* const* d_in, const int* in_sizes, int n_in,
                              void* d_out, int out_size, void* d_ws, size_t ws_size,
                              hipStream_t stream)
{
  const float* x      = (const float*)d_in[0];
  const float* u0v    = (const float*)d_in[1];
  const float* Te     = (const float*)d_in[2];
  const float* Tsv    = (const float*)d_in[3];
  const float* Tdcv   = (const float*)d_in[4];
  const float* Wsv    = (const float*)d_in[5];
  const float* Wdcv   = (const float*)d_in[6];
  const float* lamr   = (const float*)d_in[7];
  const float* Gr     = (const float*)d_in[8];
  const float* I0     = (const float*)d_in[9];
  const float* bmat   = (const float*)d_in[10];
  const float* asvr   = (const float*)d_in[11];
  const float* tausvr = (const float*)d_in[12];
  const float* adcvr  = (const float*)d_in[13];
  const float* taudcvr= (const float*)d_in[14];
  const int*   signt  = (const int*)d_in[15];
  uint8_t* ws = (uint8_t*)d_ws;

  hipLaunchKernelGGL(prepA_kernel, dim3(NN), dim3(64), 0, stream, Te, Tsv, Tdcv, ws);
  hipLaunchKernelGGL(prepB_kernel, dim3(1), dim3(PTPB), 0, stream,
      lamr, Gr, I0, asvr, tausvr, adcvr, taudcvr, ws);
  hipLaunchKernelGGL(prepC_kernel, dim3(PTPB), dim3(64), 0, stream,
      Te, Tsv, Tdcv, Wsv, Wdcv, Gr, signt, ws);
  hipLaunchKernelGGL(stim_kernel,
      dim3((unsigned)(((int64_t)BATCH*TSTEPS*NN + 255)/256)), dim3(256), 0, stream,
      x, bmat, (float*)d_out);
  hipLaunchKernelGGL(sim_kernel, dim3(BATCH), dim3(STPB), 0, stream,
      u0v, ws, (float*)d_out);
}